// Round 2
// baseline (488.101 us; speedup 1.0000x reference)
//
#include <hip/hip_runtime.h>

// Problem geometry (fixed by reference):
//   inputs (8, 64, 16, 32, 32) fp32, embedding (512, 64) fp32
//   N = 8*16*32*32 = 131072 positions, D = 64, K = 512
//   d_out layout (fp32): [0, 8388608) quantized_st, [8388608] loss,
//                        [8388609, 8519681) indices (as float)
#define SPATIAL   16384      // 16*32*32
#define DIM       64
#define KCODES    512
#define NPOS      131072
#define QST_ELEMS 8388608
#define LOSS_OFF  8388608
#define IDX_OFF   8388609

#define POS_PER_BLOCK 64
#define NBLOCKS   (NPOS / POS_PER_BLOCK)   // 2048
#define K_PER_WAVE (KCODES / 4)            // 128

// --- non-contractable fp32 ops (match numpy's plain mul/add/sub) ---
__device__ __forceinline__ float mul_rn(float a, float b) {
#pragma clang fp contract(off)
    return a * b;
}
__device__ __forceinline__ float add_rn(float a, float b) {
#pragma clang fp contract(off)
    return a + b;
}
__device__ __forceinline__ float sub_rn(float a, float b) {
#pragma clang fp contract(off)
    return a - b;
}

// numpy pairwise_sum for n=64 contiguous fp32: 8 accumulators striding by 8,
// then ((r0+r1)+(r2+r3))+((r4+r5)+(r6+r7)).  Input here: squares of v[].
__device__ __forceinline__ float np_sumsq64(const float* v) {
    float r[8];
#pragma unroll
    for (int j = 0; j < 8; ++j) r[j] = mul_rn(v[j], v[j]);
#pragma unroll
    for (int i = 8; i < 64; i += 8) {
#pragma unroll
        for (int j = 0; j < 8; ++j) r[j] = add_rn(r[j], mul_rn(v[i + j], v[i + j]));
    }
    return add_rn(add_rn(add_rn(r[0], r[1]), add_rn(r[2], r[3])),
                  add_rn(add_rn(r[4], r[5]), add_rn(r[6], r[7])));
}

// e2[k] = np.sum(embedding**2, axis=1), bit-exact numpy pairwise order
__global__ void vq_e2_kernel(const float* __restrict__ emb, float* __restrict__ e2) {
    int k = threadIdx.x;
    if (k >= KCODES) return;
    float v[DIM];
#pragma unroll
    for (int d = 0; d < DIM; ++d) v[d] = emb[k * DIM + d];
    e2[k] = np_sumsq64(v);
}

// Main: block = 256 thr (4 waves) owns 64 positions; wave w scans codes
// [128w, 128w+128).  LDS reduce (ascending wave order, strict <) reproduces
// the serial first-min argmin exactly.
__global__ __launch_bounds__(256, 2) void vq_main_kernel(
        const float* __restrict__ in, const float* __restrict__ emb,
        const float* __restrict__ e2, float* __restrict__ out,
        double* __restrict__ losspart) {
    const int lane = threadIdx.x & 63;
    const int wave = threadIdx.x >> 6;        // 0..3
    const int p = blockIdx.x * POS_PER_BLOCK + lane;  // this lane's position
    const int b = p >> 14;
    const int s = p & 16383;
    const float* xin = in + (size_t)b * (DIM * SPATIAL) + s;

    // load the 64-channel vector (coalesced across lanes for each d)
    float x[DIM];
#pragma unroll
    for (int d = 0; d < DIM; ++d) x[d] = xin[(size_t)d * SPATIAL];
    // pin x in VGPRs: block rematerialization of the global loads
#pragma unroll
    for (int d = 0; d < DIM; ++d) asm volatile("" : "+v"(x[d]));

    // x2 bit-exact vs numpy np.sum(flat**2, axis=1)
    const float x2 = np_sumsq64(x);

    // distance scan over this wave's k-range
    const int kstart = wave * K_PER_WAVE;
    float best = __builtin_inff();
    int bidx = kstart;
#pragma unroll 2
    for (int kk = 0; kk < K_PER_WAVE; ++kk) {
        const int k = kstart + kk;
        const float* ek = emb + k * DIM;      // wave-uniform
        float acc = 0.0f;
#pragma unroll
        for (int d = 0; d < DIM; ++d) acc = __builtin_fmaf(x[d], ek[d], acc);
        float t1, dist;
        {
#pragma clang fp contract(off)
            t1 = x2 + e2[k];
            dist = t1 - 2.0f * acc;           // 2.0f*acc exact
        }
        if (dist < best) { best = dist; bidx = k; }
    }

    // cross-wave argmin reduce (ascending wave order == ascending k ranges)
    __shared__ float sbest[4][POS_PER_BLOCK];
    __shared__ int   sidx[4][POS_PER_BLOCK];
    sbest[wave][lane] = best;
    sidx[wave][lane]  = bidx;
    __syncthreads();
    float fb = sbest[0][lane];
    int   fi = sidx[0][lane];
#pragma unroll
    for (int w = 1; w < 4; ++w) {
        float dv = sbest[w][lane];
        int   iv = sidx[w][lane];
        if (dv < fb) { fb = dv; fi = iv; }
    }

    if (wave == 0) out[IDX_OFF + p] = (float)fi;

    // epilogue: wave w handles channels [16w, 16w+16) of its lane's position.
    // x values for this slice are re-read from global (L1-hot) to avoid
    // runtime indexing into the x[] register array.
    const int d0 = wave * 16;
    const float* eq = emb + (size_t)fi * DIM + d0;   // 16B-aligned
    float* oq = out + (size_t)b * (DIM * SPATIAL) + s;
    double lsum = 0.0;
#pragma unroll
    for (int j = 0; j < 4; ++j) {
        float4 q4 = *(const float4*)(eq + 4 * j);
        float qv[4] = {q4.x, q4.y, q4.z, q4.w};
#pragma unroll
        for (int c = 0; c < 4; ++c) {
            int d = d0 + 4 * j + c;
            float xv = xin[(size_t)d * SPATIAL];
            float diff = sub_rn(qv[c], xv);          // fl(q - x)
            float qst  = add_rn(xv, diff);           // fl(x + fl(q - x))
            oq[(size_t)d * SPATIAL] = qst;
            float sq = mul_rn(diff, diff);
            lsum += (double)sq;
        }
    }

    // deterministic loss partial: wave shuffle-reduce, then ordered sum of the
    // 4 wave partials by thread 0 -> losspart[blockIdx.x]
#pragma unroll
    for (int off = 32; off > 0; off >>= 1) lsum += __shfl_down(lsum, off, 64);
    __shared__ double lpart[4];
    if (lane == 0) lpart[wave] = lsum;
    __syncthreads();
    if (threadIdx.x == 0) {
        double t = ((lpart[0] + lpart[1]) + lpart[2]) + lpart[3];
        losspart[blockIdx.x] = t;
    }
}

// reduce 2048 block partials (deterministic fixed-order tree) -> loss scalar
__global__ void vq_finalize_kernel(const double* __restrict__ part,
                                   float* __restrict__ out) {
    __shared__ double sdata[256];
    int t = threadIdx.x;
    double a = 0.0;
#pragma unroll
    for (int i = 0; i < NBLOCKS / 256; ++i) a += part[t + 256 * i];
    sdata[t] = a;
    __syncthreads();
    for (int stride = 128; stride > 0; stride >>= 1) {
        if (t < stride) sdata[t] = sdata[t] + sdata[t + stride];
        __syncthreads();
    }
    if (t == 0) {
        double m = sdata[0] / (double)QST_ELEMS;
        float mf = (float)m;
        out[LOSS_OFF] = add_rn(mf, mul_rn(0.25f, mf));
    }
}

extern "C" void kernel_launch(void* const* d_in, const int* in_sizes, int n_in,
                              void* d_out, int out_size, void* d_ws, size_t ws_size,
                              hipStream_t stream) {
    const float* in  = (const float*)d_in[0];
    const float* emb = (const float*)d_in[1];
    float* out = (float*)d_out;
    double* losspart = (double*)d_ws;                       // 2048 doubles = 16 KB
    float* e2 = (float*)((char*)d_ws + NBLOCKS * sizeof(double));  // 512 floats

    vq_e2_kernel<<<1, KCODES, 0, stream>>>(emb, e2);
    vq_main_kernel<<<NBLOCKS, 256, 0, stream>>>(in, emb, e2, out, losspart);
    vq_finalize_kernel<<<1, 256, 0, stream>>>(losspart, out);
}

// Round 3
// 157.176 us; speedup vs baseline: 3.1054x; 3.1054x over previous
//
#include <hip/hip_runtime.h>

// inputs (8, 64, 16, 32, 32) fp32, embedding (512, 64) fp32
// N = 131072 positions, D = 64, K = 512
// d_out (fp32): [0, 8388608) quantized_st, [8388608] loss, [8388609, ...) indices
#define SPATIAL   16384
#define DIM       64
#define KCODES    512
#define NPOS      131072
#define QST_ELEMS 8388608
#define LOSS_OFF  8388608
#define IDX_OFF   8388609
#define KTILE     256
#define NKTILES   (KCODES / KTILE)     // 2
#define NBLOCKS   (NPOS / 256)         // 512 blocks, 1 thread = 1 position

// --- non-contractable fp32 ops (match numpy's plain mul/add/sub) ---
__device__ __forceinline__ float mul_rn(float a, float b) {
#pragma clang fp contract(off)
    return a * b;
}
__device__ __forceinline__ float add_rn(float a, float b) {
#pragma clang fp contract(off)
    return a + b;
}
__device__ __forceinline__ float sub_rn(float a, float b) {
#pragma clang fp contract(off)
    return a - b;
}

// numpy pairwise_sum for n=64: 8 accumulators strided by 8, then
// ((r0+r1)+(r2+r3))+((r4+r5)+(r6+r7))
__device__ __forceinline__ float np_sumsq64(const float* v) {
    float r[8];
#pragma unroll
    for (int j = 0; j < 8; ++j) r[j] = mul_rn(v[j], v[j]);
#pragma unroll
    for (int i = 8; i < 64; i += 8) {
#pragma unroll
        for (int j = 0; j < 8; ++j) r[j] = add_rn(r[j], mul_rn(v[i + j], v[i + j]));
    }
    return add_rn(add_rn(add_rn(r[0], r[1]), add_rn(r[2], r[3])),
                  add_rn(add_rn(r[4], r[5]), add_rn(r[6], r[7])));
}

// e2[k] = np.sum(embedding**2, axis=1), bit-exact numpy pairwise order
__global__ void vq_e2_kernel(const float* __restrict__ emb, float* __restrict__ e2) {
    int k = threadIdx.x;
    if (k >= KCODES) return;
    float v[DIM];
#pragma unroll
    for (int d = 0; d < DIM; ++d) v[d] = emb[k * DIM + d];
    e2[k] = np_sumsq64(v);
}

// ---- x held in 16 NAMED float4s (no array -> no spill path) ----
#define DECLX float4 x0,x1,x2q,x3,x4,x5,x6,x7,x8,x9,x10,x11,x12,x13,x14,x15;
// note: x2 name is taken by the sum-of-squares scalar; quad 2 is x2q

#define LOADX(v,q) \
    v.x = xin[(size_t)(4*(q)+0)*SPATIAL]; \
    v.y = xin[(size_t)(4*(q)+1)*SPATIAL]; \
    v.z = xin[(size_t)(4*(q)+2)*SPATIAL]; \
    v.w = xin[(size_t)(4*(q)+3)*SPATIAL];

// numpy 8-accumulator sumsq over named quads: element d=8m+j -> even quad j=c, odd quad j=4+c
#define SQA(ve,vo) \
    r0 = add_rn(r0, mul_rn(ve.x, ve.x)); r1 = add_rn(r1, mul_rn(ve.y, ve.y)); \
    r2 = add_rn(r2, mul_rn(ve.z, ve.z)); r3 = add_rn(r3, mul_rn(ve.w, ve.w)); \
    r4 = add_rn(r4, mul_rn(vo.x, vo.x)); r5 = add_rn(r5, mul_rn(vo.y, vo.y)); \
    r6 = add_rn(r6, mul_rn(vo.z, vo.z)); r7 = add_rn(r7, mul_rn(vo.w, vo.w));

// two interleaved serial-ascending-d FMA chains (codes a and b)
#define DSTEP(v,q) { \
    float4 ea = era[q], eb = erb[q]; \
    acca = __builtin_fmaf(v.x, ea.x, acca); accb = __builtin_fmaf(v.x, eb.x, accb); \
    acca = __builtin_fmaf(v.y, ea.y, acca); accb = __builtin_fmaf(v.y, eb.y, accb); \
    acca = __builtin_fmaf(v.z, ea.z, acca); accb = __builtin_fmaf(v.z, eb.z, accb); \
    acca = __builtin_fmaf(v.w, ea.w, acca); accb = __builtin_fmaf(v.w, eb.w, accb); }

#define EPIQ(v,q) { \
    float4 e4 = eq4[q]; \
    float dd; \
    dd = sub_rn(e4.x, v.x); oq[(size_t)(4*(q)+0)*SPATIAL] = add_rn(v.x, dd); lsum += (double)mul_rn(dd, dd); \
    dd = sub_rn(e4.y, v.y); oq[(size_t)(4*(q)+1)*SPATIAL] = add_rn(v.y, dd); lsum += (double)mul_rn(dd, dd); \
    dd = sub_rn(e4.z, v.z); oq[(size_t)(4*(q)+2)*SPATIAL] = add_rn(v.z, dd); lsum += (double)mul_rn(dd, dd); \
    dd = sub_rn(e4.w, v.w); oq[(size_t)(4*(q)+3)*SPATIAL] = add_rn(v.w, dd); lsum += (double)mul_rn(dd, dd); }

__global__ __launch_bounds__(256, 2) void vq_main_kernel(
        const float* __restrict__ in, const float* __restrict__ emb,
        const float* __restrict__ e2, float* __restrict__ out,
        double* __restrict__ losspart) {
    __shared__ float4 sev[KTILE * DIM / 4];   // 64 KB embedding tile
    __shared__ float  se2[KTILE];             // 1 KB
    __shared__ double lpart[4];

    const int t = threadIdx.x;
    const int p = blockIdx.x * 256 + t;       // this thread's position
    const int b = p >> 14;
    const int s = p & 16383;
    const float* xin = in + (size_t)b * (DIM * SPATIAL) + s;

    DECLX
    LOADX(x0, 0)  LOADX(x1, 1)  LOADX(x2q, 2) LOADX(x3, 3)
    LOADX(x4, 4)  LOADX(x5, 5)  LOADX(x6, 6)  LOADX(x7, 7)
    LOADX(x8, 8)  LOADX(x9, 9)  LOADX(x10,10) LOADX(x11,11)
    LOADX(x12,12) LOADX(x13,13) LOADX(x14,14) LOADX(x15,15)

    // x2 = np.sum(flat**2) in numpy pairwise order
    float r0 = mul_rn(x0.x, x0.x), r1 = mul_rn(x0.y, x0.y);
    float r2 = mul_rn(x0.z, x0.z), r3 = mul_rn(x0.w, x0.w);
    float r4 = mul_rn(x1.x, x1.x), r5 = mul_rn(x1.y, x1.y);
    float r6 = mul_rn(x1.z, x1.z), r7 = mul_rn(x1.w, x1.w);
    SQA(x2q, x3) SQA(x4, x5) SQA(x6, x7) SQA(x8, x9)
    SQA(x10, x11) SQA(x12, x13) SQA(x14, x15)
    const float x2 = add_rn(add_rn(add_rn(r0, r1), add_rn(r2, r3)),
                            add_rn(add_rn(r4, r5), add_rn(r6, r7)));

    float best = __builtin_inff();
    int bidx = 0;

    for (int tile = 0; tile < NKTILES; ++tile) {
        // stage 256 codes (64 KB) coalesced: 16 float4s per thread
        const float4* esrc = (const float4*)(emb + (size_t)tile * KTILE * DIM);
#pragma unroll
        for (int i = 0; i < 16; ++i) sev[t + i * 256] = esrc[t + i * 256];
        if (t < KTILE / 4) ((float4*)se2)[t] = ((const float4*)(e2 + tile * KTILE))[t];
        __syncthreads();

        const int kbase = tile * KTILE;
        for (int kk = 0; kk < KTILE; kk += 2) {
            const float4* era = sev + (size_t)kk * (DIM / 4);  // broadcast reads
            const float4* erb = era + (DIM / 4);
            float acca = 0.0f, accb = 0.0f;
            DSTEP(x0, 0)  DSTEP(x1, 1)  DSTEP(x2q, 2) DSTEP(x3, 3)
            DSTEP(x4, 4)  DSTEP(x5, 5)  DSTEP(x6, 6)  DSTEP(x7, 7)
            DSTEP(x8, 8)  DSTEP(x9, 9)  DSTEP(x10,10) DSTEP(x11,11)
            DSTEP(x12,12) DSTEP(x13,13) DSTEP(x14,14) DSTEP(x15,15)
            float twoa = mul_rn(2.0f, acca);            // exact
            float twob = mul_rn(2.0f, accb);
            float dista = sub_rn(add_rn(x2, se2[kk]),     twoa);
            float distb = sub_rn(add_rn(x2, se2[kk + 1]), twob);
            if (dista < best) { best = dista; bidx = kbase + kk; }
            if (distb < best) { best = distb; bidx = kbase + kk + 1; }
        }
        __syncthreads();
    }

    out[IDX_OFF + p] = (float)bidx;

    // epilogue: qst + loss from registers; codebook row gather is L2-hot
    const float4* eq4 = (const float4*)(emb + (size_t)bidx * DIM);
    float* oq = out + (size_t)b * (DIM * SPATIAL) + s;
    double lsum = 0.0;
    EPIQ(x0, 0)  EPIQ(x1, 1)  EPIQ(x2q, 2) EPIQ(x3, 3)
    EPIQ(x4, 4)  EPIQ(x5, 5)  EPIQ(x6, 6)  EPIQ(x7, 7)
    EPIQ(x8, 8)  EPIQ(x9, 9)  EPIQ(x10,10) EPIQ(x11,11)
    EPIQ(x12,12) EPIQ(x13,13) EPIQ(x14,14) EPIQ(x15,15)

    // deterministic loss partial: wave shuffle reduce -> ordered 4-wave sum
#pragma unroll
    for (int off = 32; off > 0; off >>= 1) lsum += __shfl_down(lsum, off, 64);
    const int lane = t & 63, wave = t >> 6;
    if (lane == 0) lpart[wave] = lsum;
    __syncthreads();
    if (t == 0) losspart[blockIdx.x] = ((lpart[0] + lpart[1]) + lpart[2]) + lpart[3];
}

// reduce 512 block partials (deterministic fixed-order tree) -> loss scalar
__global__ void vq_finalize_kernel(const double* __restrict__ part,
                                   float* __restrict__ out) {
    __shared__ double sdata[256];
    int t = threadIdx.x;
    sdata[t] = part[t] + part[t + 256];
    __syncthreads();
    for (int stride = 128; stride > 0; stride >>= 1) {
        if (t < stride) sdata[t] = sdata[t] + sdata[t + stride];
        __syncthreads();
    }
    if (t == 0) {
        double m = sdata[0] / (double)QST_ELEMS;
        float mf = (float)m;
        out[LOSS_OFF] = add_rn(mf, mul_rn(0.25f, mf));
    }
}

extern "C" void kernel_launch(void* const* d_in, const int* in_sizes, int n_in,
                              void* d_out, int out_size, void* d_ws, size_t ws_size,
                              hipStream_t stream) {
    const float* in  = (const float*)d_in[0];
    const float* emb = (const float*)d_in[1];
    float* out = (float*)d_out;
    double* losspart = (double*)d_ws;                              // 512 doubles
    float* e2 = (float*)((char*)d_ws + NBLOCKS * sizeof(double));  // 512 floats

    vq_e2_kernel<<<1, KCODES, 0, stream>>>(emb, e2);
    vq_main_kernel<<<NBLOCKS, 256, 0, stream>>>(in, emb, e2, out, losspart);
    vq_finalize_kernel<<<1, 256, 0, stream>>>(losspart, out);
}